// Round 4
// baseline (314.228 us; speedup 1.0000x reference)
//
#include <hip/hip_runtime.h>

// Chamfer distance, B=8, N=M=4096, fp32 — single fused kernel.
// Phase 1: per (qblk, chunk, dirb) block: 2048 queries x 128 LDS-staged db
//          points, partial mins (|b|^2 - 2 q.b) -> P.  (identical to R2 K1)
// Grid barrier: all 1024 blocks co-resident (256 thr, LB(256,4) -> 4 blk/CU).
// Phase 2: each block reduces 64 slots over 32 chunks, sqrt, deterministic
//          fixed-point u64 sum; last block writes the loss.

#define BATCH 8
#define NPTS 4096
#define THREADS 256
#define TQ 8
#define QB (TQ*THREADS)          // 2048
#define QBLKS (NPTS/QB)          // 2
#define CHUNKS 32
#define CHUNK (NPTS/CHUNKS)      // 128
#define NSLOT (2*BATCH*NPTS)     // 65536
#define GRID (QBLKS*CHUNKS*2*BATCH) // 1024
#define SLOTS_PER_BLK (NSLOT/GRID)  // 64
#define FIX_SCALE 4294967296.0   // 2^32

__global__ __launch_bounds__(THREADS, 4) void cd_fused(
        const float* __restrict__ pred,
        const float* __restrict__ targ,
        float* __restrict__ P,
        unsigned int* __restrict__ hdr,  // [0]=done1 [1]=done2 [2..3]=u64 sum
        float* __restrict__ out) {
    const int bid   = blockIdx.x;
    const int qblk  = bid & (QBLKS - 1);
    const int chunk = (bid >> 1) & (CHUNKS - 1);
    const int dirb  = bid >> 6;          // dir*BATCH + b
    const int dir   = dirb >> 3;
    const int b     = dirb & 7;
    const int tid   = threadIdx.x;
    const float* Q  = dir ? targ : pred;
    const float* Db = dir ? pred : targ;

    // ---- phase 1: stage db chunk into LDS as (x,y,z,|b|^2) ----
    __shared__ float4 sdb[CHUNK];
    if (tid < CHUNK) {
        const float* p = Db + ((size_t)b * NPTS + (size_t)chunk * CHUNK + tid) * 3;
        float x = p[0], y = p[1], z = p[2];
        sdb[tid] = make_float4(x, y, z, fmaf(x, x, fmaf(y, y, z * z)));
    }
    __syncthreads();

    float qx[TQ], qy[TQ], qz[TQ], m[TQ];
    const int q0 = qblk * QB + tid;
    #pragma unroll
    for (int k = 0; k < TQ; ++k) {
        const float* p = Q + ((size_t)b * NPTS + q0 + k * THREADS) * 3;
        qx[k] = -2.f * p[0]; qy[k] = -2.f * p[1]; qz[k] = -2.f * p[2];
        m[k]  = __uint_as_float(0x7F800000u);
    }

    #pragma unroll 4
    for (int j = 0; j < CHUNK; j += 2) {
        float4 b0 = sdb[j];
        float4 b1 = sdb[j + 1];
        #pragma unroll
        for (int k = 0; k < TQ; ++k) {
            float t0 = fmaf(qx[k], b0.x, fmaf(qy[k], b0.y, fmaf(qz[k], b0.z, b0.w)));
            float t1 = fmaf(qx[k], b1.x, fmaf(qy[k], b1.y, fmaf(qz[k], b1.z, b1.w)));
            m[k] = fminf(m[k], fminf(t0, t1));  // -> v_min3_f32
        }
    }

    {
        float* o = P + (size_t)chunk * NSLOT + (size_t)dirb * NPTS + q0;
        #pragma unroll
        for (int k = 0; k < TQ; ++k) o[k * THREADS] = m[k];
    }

    // ---- grid barrier (all blocks co-resident by construction) ----
    __threadfence();       // make P stores device-visible
    __syncthreads();
    if (tid == 0) {
        __hip_atomic_fetch_add(&hdr[0], 1u, __ATOMIC_RELEASE, __HIP_MEMORY_SCOPE_AGENT);
        while (__hip_atomic_load(&hdr[0], __ATOMIC_ACQUIRE, __HIP_MEMORY_SCOPE_AGENT) < GRID)
            __builtin_amdgcn_s_sleep(8);
    }
    __syncthreads();
    __threadfence();       // acquire side: discard stale cached lines

    // ---- phase 2: wave 0 reduces this block's 64 slots ----
    if (tid < 64) {
        const int slot  = bid * SLOTS_PER_BLK + tid;
        const int dirb2 = slot >> 12;
        const int q     = slot & (NPTS - 1);
        const int b2    = dirb2 & 7;
        const float* p  = ((dirb2 >> 3) ? targ : pred) + ((size_t)b2 * NPTS + q) * 3;
        float x = p[0], y = p[1], z = p[2];
        float nq = fmaf(x, x, fmaf(y, y, z * z));

        float mn = __uint_as_float(0x7F800000u);
        #pragma unroll
        for (int c = 0; c < CHUNKS; c += 2)
            mn = fminf(mn, fminf(P[(size_t)c * NSLOT + slot],
                                 P[(size_t)(c + 1) * NSLOT + slot]));

        float d = sqrtf(fmaxf(nq + mn, 0.f));
        #pragma unroll
        for (int off = 32; off > 0; off >>= 1) d += __shfl_down(d, off);

        if (tid == 0) {
            unsigned long long fx = (unsigned long long)((double)d * FIX_SCALE);
            atomicAdd((unsigned long long*)(hdr + 2), fx);
            __threadfence();
            unsigned int old = __hip_atomic_fetch_add(&hdr[1], 1u,
                    __ATOMIC_ACQ_REL, __HIP_MEMORY_SCOPE_AGENT);
            if (old == GRID - 1) {
                unsigned long long tot = __hip_atomic_load(
                        (unsigned long long*)(hdr + 2),
                        __ATOMIC_RELAXED, __HIP_MEMORY_SCOPE_AGENT);
                out[0] = (float)(((double)tot / FIX_SCALE) / (double)(BATCH * NPTS));
            }
        }
    }
}

extern "C" void kernel_launch(void* const* d_in, const int* in_sizes, int n_in,
                              void* d_out, int out_size, void* d_ws, size_t ws_size,
                              hipStream_t stream) {
    const float* pred = (const float*)d_in[0];
    const float* targ = (const float*)d_in[1];
    unsigned int* hdr = (unsigned int*)d_ws;       // 64 B header
    float* P   = (float*)((char*)d_ws + 64);       // 8 MB partials
    float* out = (float*)d_out;

    hipMemsetAsync(d_ws, 0, 64, stream);           // zero header (graph-safe)
    cd_fused<<<GRID, THREADS, 0, stream>>>(pred, targ, P, hdr, out);
}

// Round 5
// 33.884 us; speedup vs baseline: 9.2737x; 9.2737x over previous
//
#include <hip/hip_runtime.h>

// Chamfer distance, B=8, N=M=4096, fp32 — 3 dispatches, zero atomics.
// K1 cd_partial: per (qblk, chunk, dirb) block: 2048 queries x 128 LDS-staged
//                db points; partial min of (|b|^2 - 2 q.b) -> P. (R2 K1)
// K2 cd_reduce:  1 thread/slot: min over 32 chunks, +|q|^2, sqrt, block tree
//                sum -> Bsum[256]. No atomics.
// K3 cd_final:   1 wave sums Bsum[256] -> loss. Deterministic order.

#define BATCH 8
#define NPTS 4096
#define THREADS 256
#define TQ 8
#define QB (TQ*THREADS)          // 2048
#define QBLKS (NPTS/QB)          // 2
#define CHUNKS 32
#define CHUNK (NPTS/CHUNKS)      // 128
#define NSLOT (2*BATCH*NPTS)     // 65536
#define RBLKS (NSLOT/256)        // 256 reduce blocks

__global__ __launch_bounds__(THREADS, 4) void cd_partial(
        const float* __restrict__ pred,
        const float* __restrict__ targ,
        float* __restrict__ P) {
    const int qblk  = blockIdx.x;      // 0..QBLKS-1
    const int chunk = blockIdx.y;      // 0..CHUNKS-1
    const int dirb  = blockIdx.z;      // dir*BATCH + b
    const int dir   = dirb >> 3;
    const int b     = dirb & 7;
    const int tid   = threadIdx.x;
    const float* Q  = dir ? targ : pred;
    const float* Db = dir ? pred : targ;

    __shared__ float4 sdb[CHUNK];
    if (tid < CHUNK) {
        const float* p = Db + ((size_t)b * NPTS + (size_t)chunk * CHUNK + tid) * 3;
        float x = p[0], y = p[1], z = p[2];
        sdb[tid] = make_float4(x, y, z, fmaf(x, x, fmaf(y, y, z * z)));
    }
    __syncthreads();

    float qx[TQ], qy[TQ], qz[TQ], m[TQ];
    const int q0 = qblk * QB + tid;
    #pragma unroll
    for (int k = 0; k < TQ; ++k) {
        const float* p = Q + ((size_t)b * NPTS + q0 + k * THREADS) * 3;
        qx[k] = -2.f * p[0]; qy[k] = -2.f * p[1]; qz[k] = -2.f * p[2];
        m[k]  = __uint_as_float(0x7F800000u);
    }

    #pragma unroll 4
    for (int j = 0; j < CHUNK; j += 2) {
        float4 b0 = sdb[j];
        float4 b1 = sdb[j + 1];
        #pragma unroll
        for (int k = 0; k < TQ; ++k) {
            float t0 = fmaf(qx[k], b0.x, fmaf(qy[k], b0.y, fmaf(qz[k], b0.z, b0.w)));
            float t1 = fmaf(qx[k], b1.x, fmaf(qy[k], b1.y, fmaf(qz[k], b1.z, b1.w)));
            m[k] = fminf(m[k], fminf(t0, t1));  // -> v_min3_f32
        }
    }

    float* o = P + (size_t)chunk * NSLOT + (size_t)dirb * NPTS + q0;
    #pragma unroll
    for (int k = 0; k < TQ; ++k) o[k * THREADS] = m[k];
}

__global__ __launch_bounds__(256) void cd_reduce(
        const float* __restrict__ pred,
        const float* __restrict__ targ,
        const float* __restrict__ P,
        float* __restrict__ Bsum) {
    const int tid  = threadIdx.x;
    const int slot = blockIdx.x * 256 + tid;   // 0..NSLOT-1
    const int dirb = slot >> 12;
    const int q    = slot & (NPTS - 1);
    const int b    = dirb & 7;

    const float* p = ((dirb >> 3) ? targ : pred) + ((size_t)b * NPTS + q) * 3;
    float x = p[0], y = p[1], z = p[2];
    float nq = fmaf(x, x, fmaf(y, y, z * z));

    float m = __uint_as_float(0x7F800000u);
    #pragma unroll
    for (int c = 0; c < CHUNKS; c += 2)
        m = fminf(m, fminf(P[(size_t)c * NSLOT + slot],
                           P[(size_t)(c + 1) * NSLOT + slot]));

    float s = sqrtf(fmaxf(nq + m, 0.f));
    #pragma unroll
    for (int off = 32; off > 0; off >>= 1) s += __shfl_down(s, off);

    __shared__ float wsum[4];
    if ((tid & 63) == 0) wsum[tid >> 6] = s;
    __syncthreads();
    if (tid == 0)
        Bsum[blockIdx.x] = (wsum[0] + wsum[1]) + (wsum[2] + wsum[3]);
}

__global__ __launch_bounds__(64) void cd_final(
        const float* __restrict__ Bsum, float* __restrict__ out) {
    const int tid = threadIdx.x;   // one wave
    float s = 0.f;
    #pragma unroll
    for (int i = 0; i < RBLKS; i += 64) s += Bsum[i + tid];
    #pragma unroll
    for (int off = 32; off > 0; off >>= 1) s += __shfl_down(s, off);
    if (tid == 0) out[0] = s * (1.0f / (float)(BATCH * NPTS));
}

extern "C" void kernel_launch(void* const* d_in, const int* in_sizes, int n_in,
                              void* d_out, int out_size, void* d_ws, size_t ws_size,
                              hipStream_t stream) {
    const float* pred = (const float*)d_in[0];
    const float* targ = (const float*)d_in[1];
    float* P    = (float*)d_ws;                                   // 8 MB partials
    float* Bsum = (float*)((char*)d_ws + (size_t)CHUNKS * NSLOT * 4); // 1 KB
    float* out  = (float*)d_out;

    cd_partial<<<dim3(QBLKS, CHUNKS, 2 * BATCH), THREADS, 0, stream>>>(pred, targ, P);
    cd_reduce<<<RBLKS, 256, 0, stream>>>(pred, targ, P, Bsum);
    cd_final<<<1, 64, 0, stream>>>(Bsum, out);
}